// Round 5
// baseline (442.708 us; speedup 1.0000x reference)
//
#include <hip/hip_runtime.h>
#include <cstddef>
#include <cstdint>

// ---------------------------------------------------------------------------
// MultiGroupDMoN forward, reduced algebraically:
//   tr_g   = sum_e val * dot(S[src], S[dst])     (fp8 gathers, edge kernel)
//   w_g[i] = sum_{e:dst=i} val                   (scalar atomics, edge kernel)
//   gdS_g  = sum_i w_g[i] * S[i,:], m_g = sum w  (dense pass, exact fp32)
// ws layout (floats):
//   [OFF_E .. +3*18*EGRID)   edge/dense partials [g][slot][col]  (memset 0)
//   [OFF_R .. +4112)         reduced P[4096]+cs[16]              (memset 0)
//   [OFF_G .. +64)           G54 reduced accumulators
//   [OFF_W .. +3n)           w histograms (3 graphs)             (memset 0)
//   [OFF_F8.. +4n)           fp8 S (n rows x 16 bytes, as u32)
//   [OFF_P .. +grid1*4112)   per-block k_rows partials
// ---------------------------------------------------------------------------

#define G1_MAX   1024
#define EGRID    2048
#define NSEG     16
#define OFF_E    0
#define SZ_E     (3 * 18 * EGRID)
#define OFF_R    (OFF_E + SZ_E)
#define OFF_G    (OFF_R + 4112)
#define OFF_W    (OFF_G + 64)

#if __has_builtin(__builtin_amdgcn_cvt_pk_f32_fp8)
#define HW_FP8 1
#endif

// ---- software e4m3fn encode (used once per S element in k_rows) ----
__device__ __forceinline__ unsigned f32_to_e4m3(float f)
{
    unsigned bits = __float_as_uint(f);
    unsigned s = bits >> 31;
    int e32 = (int)((bits >> 23) & 255);
    unsigned m23 = bits & 0x7FFFFF;
    int e = e32 - 120;                        // e4m3 biased exponent
    unsigned out;
    if (e32 == 0) out = 0;                    // fp32 denorm -> 0
    else if (e <= 0) {                        // e4m3 denorm: round(|f|*512)
        float av = fabsf(f);
        int q = (int)(av * 512.0f + 0.5f);    // 0..8
        out = (unsigned)q;                    // q==8 == min normal (e=1,m=0)
    } else if (e > 15) out = (15u << 3) | 6u; // clamp (never hit for S<=1)
    else {
        unsigned m3 = (m23 + 0x80000u) >> 20;
        if (m3 == 8u) { m3 = 0u; ++e; if (e > 15) { e = 15; m3 = 6u; } }
        out = ((unsigned)e << 3) | m3;
    }
    return out | (s << 7);
}

// ---- decode 4+4 fp8 bytes and accumulate dot ----
__device__ __forceinline__ float dot_rows(uint4 ra, uint4 rb, const float* lut)
{
    float dot = 0.f;
#ifdef HW_FP8
    #pragma unroll
    for (int j = 0; j < 4; ++j) {
        unsigned ua = (&ra.x)[j], ub = (&rb.x)[j];
        auto a0 = __builtin_amdgcn_cvt_pk_f32_fp8(ua, false);
        auto a1 = __builtin_amdgcn_cvt_pk_f32_fp8(ua, true);
        auto b0 = __builtin_amdgcn_cvt_pk_f32_fp8(ub, false);
        auto b1 = __builtin_amdgcn_cvt_pk_f32_fp8(ub, true);
        dot = fmaf(a0[0], b0[0], dot); dot = fmaf(a0[1], b0[1], dot);
        dot = fmaf(a1[0], b1[0], dot); dot = fmaf(a1[1], b1[1], dot);
    }
#else
    #pragma unroll
    for (int j = 0; j < 4; ++j) {
        unsigned ua = (&ra.x)[j], ub = (&rb.x)[j];
        #pragma unroll
        for (int q = 0; q < 4; ++q)
            dot = fmaf(lut[(ua >> (8*q)) & 255], lut[(ub >> (8*q)) & 255], dot);
    }
#endif
    return dot;
}

__global__ void __launch_bounds__(256)
k_rows(const float* __restrict__ F, const float* __restrict__ W,
       const float* __restrict__ b, float* __restrict__ S_out,
       unsigned* __restrict__ S_f8, float* __restrict__ ws_P, int n, int n_tiles)
{
    __shared__ float Wt[16][260];
    __shared__ float rows[16][260];
    __shared__ float S_lds[16][17];
    __shared__ float cs_red[256];

    const int t = threadIdx.x;

    for (int idx = t; idx < 4096; idx += 256)
        Wt[idx & 15][idx >> 4] = W[idx];

    const float bk = b[t & 15];
    const int rl = t >> 4;
    const int kl = t & 15;
    const int kp = t & 15;
    const int cp = t >> 4;

    float4 P0 = {0,0,0,0}, P1 = {0,0,0,0}, P2 = {0,0,0,0}, P3 = {0,0,0,0};
    float cs_acc = 0.f;
    __syncthreads();

    for (int tile = blockIdx.x; tile < n_tiles; tile += gridDim.x) {
        const int row0 = tile << 4;
        const float4* F4 = (const float4*)(F + (size_t)row0 * 256);
        #pragma unroll
        for (int q = 0; q < 4; ++q) {
            int idx = t + (q << 8);
            int r = idx >> 6, dc = idx & 63;
            float4 v = {0.f, 0.f, 0.f, 0.f};
            if (row0 + r < n) v = F4[idx];
            *(float4*)&rows[r][dc << 2] = v;
        }
        __syncthreads();

        float acc = 0.f;
        #pragma unroll 8
        for (int dd = 0; dd < 64; ++dd) {
            float4 f4 = *(const float4*)&rows[rl][dd << 2];
            float4 w4 = *(const float4*)&Wt[kl][dd << 2];
            acc = fmaf(f4.x, w4.x, acc);
            acc = fmaf(f4.y, w4.y, acc);
            acc = fmaf(f4.z, w4.z, acc);
            acc = fmaf(f4.w, w4.w, acc);
        }
        acc += bk;

        float mx = acc;
        #pragma unroll
        for (int o = 8; o; o >>= 1) mx = fmaxf(mx, __shfl_xor(mx, o, 16));
        float ev = __expf(acc - mx);
        float sm = ev;
        #pragma unroll
        for (int o = 8; o; o >>= 1) sm += __shfl_xor(sm, o, 16);
        float sval = ev / sm;

        const bool valid = (row0 + rl) < n;
        if (valid) {
            S_out[(((size_t)(row0 + rl)) << 4) + kl] = sval;
            cs_acc += sval;
        }
        S_lds[rl][kl] = valid ? sval : 0.f;
        __syncthreads();

        // fp8 pack: thread t<64 packs row r=t>>2, 4-elem chunk c=t&3
        if (t < 64) {
            int r = t >> 2, c = t & 3;
            int row = row0 + r;
            if (row < n) {
                unsigned u = f32_to_e4m3(S_lds[r][4*c])
                           | (f32_to_e4m3(S_lds[r][4*c+1]) << 8)
                           | (f32_to_e4m3(S_lds[r][4*c+2]) << 16)
                           | (f32_to_e4m3(S_lds[r][4*c+3]) << 24);
                S_f8[((size_t)row << 2) + c] = u;
            }
        }

        #pragma unroll 4
        for (int r = 0; r < 16; ++r) {
            float sv = S_lds[r][kp];
            const float* rp = &rows[r][cp << 4];
            float4 f0 = *(const float4*)&rp[0];
            float4 f1 = *(const float4*)&rp[4];
            float4 f2 = *(const float4*)&rp[8];
            float4 f3 = *(const float4*)&rp[12];
            P0.x = fmaf(sv, f0.x, P0.x); P0.y = fmaf(sv, f0.y, P0.y);
            P0.z = fmaf(sv, f0.z, P0.z); P0.w = fmaf(sv, f0.w, P0.w);
            P1.x = fmaf(sv, f1.x, P1.x); P1.y = fmaf(sv, f1.y, P1.y);
            P1.z = fmaf(sv, f1.z, P1.z); P1.w = fmaf(sv, f1.w, P1.w);
            P2.x = fmaf(sv, f2.x, P2.x); P2.y = fmaf(sv, f2.y, P2.y);
            P2.z = fmaf(sv, f2.z, P2.z); P2.w = fmaf(sv, f2.w, P2.w);
            P3.x = fmaf(sv, f3.x, P3.x); P3.y = fmaf(sv, f3.y, P3.y);
            P3.z = fmaf(sv, f3.z, P3.z); P3.w = fmaf(sv, f3.w, P3.w);
        }
        __syncthreads();
    }

    {
        float* dst = ws_P + (size_t)blockIdx.x * 4112 + kp * 256 + (cp << 4);
        *(float4*)&dst[0]  = P0;
        *(float4*)&dst[4]  = P1;
        *(float4*)&dst[8]  = P2;
        *(float4*)&dst[12] = P3;
    }
    cs_red[t] = cs_acc;
    __syncthreads();
    if (t < 16) {
        float ssum = 0.f;
        #pragma unroll
        for (int i = 0; i < 16; ++i) ssum += cs_red[t + (i << 4)];
        ws_P[(size_t)blockIdx.x * 4112 + 4096 + t] = ssum;
    }
}

__global__ void __launch_bounds__(256)
k_reduce(const float* __restrict__ ws_P, float* __restrict__ ws_red, int nb)
{
    const int seg  = blockIdx.x & (NSEG - 1);
    const int jblk = blockIdx.x / NSEG;
    const int idx  = jblk * 256 + threadIdx.x;
    if (idx >= 4112) return;
    const int chunk = (nb + NSEG - 1) / NSEG;
    const int b0 = seg * chunk;
    const int b1 = min(nb, b0 + chunk);
    float s = 0.f;
    for (int bb = b0; bb < b1; ++bb)
        s += ws_P[(size_t)bb * 4112 + idx];
    atomicAdd(&ws_red[idx], s);
}

// fused tr + histogram kernel over all 3 graphs
__global__ void __launch_bounds__(256, 4)
k_edge(const int* __restrict__ src0, const int* __restrict__ dst0,
       const float* __restrict__ val0, int n0,
       const int* __restrict__ src1, const int* __restrict__ dst1,
       const float* __restrict__ val1, int n1,
       const int* __restrict__ src2, const int* __restrict__ dst2,
       const float* __restrict__ val2, int n2,
       const unsigned* __restrict__ S8, float* __restrict__ w,
       float* __restrict__ ws_e, int b0, int b1, int n_nodes)
{
#ifndef HW_FP8
    __shared__ float lut[256];
    if (threadIdx.x < 256) {
        int i = threadIdx.x;
        int e_ = (i >> 3) & 15, m_ = i & 7, s_ = i >> 7;
        float v = e_ ? ldexpf((float)(8 + m_), e_ - 10) : ldexpf((float)m_, -9);
        lut[i] = s_ ? -v : v;
    }
    __syncthreads();
    const float* lutp = lut;
#else
    const float* lutp = nullptr;
#endif

    int g, bb, nblk, nE;
    const int* src; const int* dst; const float* val;
    if ((int)blockIdx.x < b0)      { g = 0; bb = blockIdx.x;      nblk = b0;             src = src0; dst = dst0; val = val0; nE = n0; }
    else if ((int)blockIdx.x < b1) { g = 1; bb = blockIdx.x - b0; nblk = b1 - b0;        src = src1; dst = dst1; val = val1; nE = n1; }
    else                           { g = 2; bb = blockIdx.x - b1; nblk = gridDim.x - b1; src = src2; dst = dst2; val = val2; nE = n2; }

    float* wg = w + (size_t)g * n_nodes;
    float tr = 0.f;

    const int nv = nE >> 3;                    // 8 edges per thread-iter
    const int4*   s4 = (const int4*)src;
    const int4*   d4 = (const int4*)dst;
    const float4* v4 = (const float4*)val;
    const int stride = nblk * 256;

    for (int i = bb * 256 + threadIdx.x; i < nv; i += stride) {
        int4   sa = s4[2*i], sb = s4[2*i+1];
        int4   da = d4[2*i], db = d4[2*i+1];
        float4 va = v4[2*i], vb = v4[2*i+1];
        int   is[8] = {sa.x, sa.y, sa.z, sa.w, sb.x, sb.y, sb.z, sb.w};
        int   id[8] = {da.x, da.y, da.z, da.w, db.x, db.y, db.z, db.w};
        float vv[8] = {va.x, va.y, va.z, va.w, vb.x, vb.y, vb.z, vb.w};
        uint4 rs[8], rd[8];
        #pragma unroll
        for (int e = 0; e < 8; ++e) {
            rs[e] = *(const uint4*)(S8 + ((size_t)is[e] << 2));
            rd[e] = *(const uint4*)(S8 + ((size_t)id[e] << 2));
        }
        #pragma unroll
        for (int e = 0; e < 8; ++e) {
            float dot = dot_rows(rs[e], rd[e], lutp);
            tr = fmaf(vv[e], dot, tr);
            atomicAdd(&wg[id[e]], vv[e]);
        }
    }

    // tail (nE % 8), block 0 of this graph only
    if (bb == 0) {
        int e = (nv << 3) + threadIdx.x;
        if (e < nE) {
            int si = src[e], di = dst[e];
            float v = val[e];
            uint4 ra = *(const uint4*)(S8 + ((size_t)si << 2));
            uint4 rb = *(const uint4*)(S8 + ((size_t)di << 2));
            tr = fmaf(v, dot_rows(ra, rb, lutp), tr);
            atomicAdd(&wg[di], v);
        }
    }

    #pragma unroll
    for (int o = 32; o; o >>= 1) tr += __shfl_xor(tr, o);
    __shared__ float wred[4];
    if ((threadIdx.x & 63) == 0) wred[threadIdx.x >> 6] = tr;
    __syncthreads();
    if (threadIdx.x == 0)
        ws_e[((size_t)g * 18 + 1) * EGRID + bb] = wred[0] + wred[1] + wred[2] + wred[3];
}

// dense pass: m_g = sum w_g, gdS_g[k] = sum_i w_g[i]*S[i][k]
__global__ void __launch_bounds__(256)
k_dense(const float* __restrict__ S, const float* __restrict__ w,
        float* __restrict__ ws_e, int n)
{
    const int t = threadIdx.x;
    const int i = blockIdx.x * 256 + t;
    float m[3] = {0.f, 0.f, 0.f};
    float gd[3][16];
    #pragma unroll
    for (int g = 0; g < 3; ++g)
        #pragma unroll
        for (int k = 0; k < 16; ++k) gd[g][k] = 0.f;

    if (i < n) {
        float w0 = w[i], w1 = w[n + i], w2 = w[2*n + i];
        m[0] = w0; m[1] = w1; m[2] = w2;
        const float4* Sr = (const float4*)(S + ((size_t)i << 4));
        #pragma unroll
        for (int j = 0; j < 4; ++j) {
            float4 sv = Sr[j];
            gd[0][4*j]   = w0*sv.x; gd[0][4*j+1] = w0*sv.y;
            gd[0][4*j+2] = w0*sv.z; gd[0][4*j+3] = w0*sv.w;
            gd[1][4*j]   = w1*sv.x; gd[1][4*j+1] = w1*sv.y;
            gd[1][4*j+2] = w1*sv.z; gd[1][4*j+3] = w1*sv.w;
            gd[2][4*j]   = w2*sv.x; gd[2][4*j+1] = w2*sv.y;
            gd[2][4*j+2] = w2*sv.z; gd[2][4*j+3] = w2*sv.w;
        }
    }

    #pragma unroll
    for (int o = 32; o; o >>= 1) {
        #pragma unroll
        for (int g = 0; g < 3; ++g) {
            m[g] += __shfl_xor(m[g], o);
            #pragma unroll
            for (int k = 0; k < 16; ++k) gd[g][k] += __shfl_xor(gd[g][k], o);
        }
    }
    __shared__ float wr[4][51];
    const int wid = t >> 6;
    if ((t & 63) == 0) {
        #pragma unroll
        for (int g = 0; g < 3; ++g) {
            wr[wid][g*17] = m[g];
            #pragma unroll
            for (int k = 0; k < 16; ++k) wr[wid][g*17 + 1 + k] = gd[g][k];
        }
    }
    __syncthreads();
    if (t < 51) {
        float s = wr[0][t] + wr[1][t] + wr[2][t] + wr[3][t];
        int g = t / 17, q = t % 17;
        int slot = (q == 0) ? 0 : (q + 1);     // q=1..16 -> slots 2..17
        ws_e[((size_t)g * 18 + slot) * EGRID + blockIdx.x] = s;
    }
}

// one block per (g,slot): reduce EGRID columns -> G54
__global__ void __launch_bounds__(256)
k_ereduce(const float* __restrict__ ws_e, float* __restrict__ G54)
{
    const int p = blockIdx.x;                  // 0..53 == g*18+slot
    const float* base = ws_e + (size_t)p * EGRID;
    const int t = threadIdx.x;
    float s = 0.f;
    for (int bb = t; bb < EGRID; bb += 256) s += base[bb];
    #pragma unroll
    for (int o = 32; o; o >>= 1) s += __shfl_xor(s, o);
    __shared__ float wr[4];
    if ((t & 63) == 0) wr[t >> 6] = s;
    __syncthreads();
    if (t == 0) G54[p] = wr[0] + wr[1] + wr[2] + wr[3];
}

__global__ void __launch_bounds__(256)
k_final(const float* __restrict__ ws_red, const float* __restrict__ G54,
        const void* __restrict__ lamda_ptr, float* __restrict__ out, int n)
{
    __shared__ float G[54];
    const int t = threadIdx.x;
    if (t < 54) G[t] = G54[t];
    __syncthreads();

    const float* P  = ws_red;
    const float* cs = ws_red + 4096;

    const float scale = 1.0507009873554805f;
    const float alpha = 1.6732632423543772f;
    for (int idx = t; idx < 4096; idx += 256) {
        int k = idx >> 8;
        float x = P[idx] / cs[k];
        float y = x > 0.f ? scale * x : scale * alpha * (expf(x) - 1.f);
        out[idx] = y;
    }

    if (t == 0) {
        int   li = *(const int*)lamda_ptr;
        float lf = *(const float*)lamda_ptr;
        float lamda = (li > -100000 && li < 100000) ? (float)li : lf;

        float m = G[0], trA = G[1];
        float ds2 = 0.f;
        for (int k = 0; k < 16; ++k) ds2 += G[2 + k] * G[2 + k];
        float spectral = -(trA - ds2 / (2.f * m)) / (2.f * m);

        float Q[2], gm[2];
        for (int g = 0; g < 2; ++g) {
            const float* Gg = G + 18 * (g + 1);
            float mg = Gg[0], trg = Gg[1];
            float gds2 = 0.f;
            for (int k = 0; k < 16; ++k) gds2 += Gg[2 + k] * Gg[2 + k];
            float safe = mg > 0.f ? mg : 1.f;
            float q = (trg - gds2 / (2.f * safe)) / (2.f * m);
            Q[g]  = mg > 0.f ? q : 0.f;
            gm[g] = mg;
        }
        float Qmin = fminf(Q[0], Q[1]);
        float gmean = 0.5f * (gm[0] + gm[1]);
        float fairness = (m / (gmean + 1e-8f)) * (-Qmin);

        float csn = 0.f;
        for (int k = 0; k < 16; ++k) csn += cs[k] * cs[k];
        float collapse = (sqrtf(csn) / (float)n) * 4.f - 1.f;

        out[4096 + (size_t)n * 16] = spectral + lamda * fairness + 0.1f * collapse;
    }
}

extern "C" void kernel_launch(void* const* d_in, const int* in_sizes, int n_in,
                              void* d_out, int out_size, void* d_ws, size_t ws_size,
                              hipStream_t stream)
{
    const float* F       = (const float*)d_in[0];
    const float* W       = (const float*)d_in[1];
    const float* b       = (const float*)d_in[2];
    const int*   adj_src = (const int*)d_in[3];
    const int*   adj_dst = (const int*)d_in[4];
    const float* adj_val = (const float*)d_in[5];
    const int*   g1_src  = (const int*)d_in[6];
    const int*   g1_dst  = (const int*)d_in[7];
    const float* g1_val  = (const float*)d_in[8];
    const int*   g2_src  = (const int*)d_in[9];
    const int*   g2_dst  = (const int*)d_in[10];
    const float* g2_val  = (const float*)d_in[11];
    const void*  lamda_p = d_in[12];

    const int n  = in_sizes[0] / 256;
    const int nE = in_sizes[3];
    const int n1 = in_sizes[6];
    const int n2 = in_sizes[9];

    float* out   = (float*)d_out;
    float* S_out = out + 4096;

    float* ws   = (float*)d_ws;
    float* ws_e = ws + OFF_E;
    float* ws_r = ws + OFF_R;
    float* ws_g = ws + OFF_G;
    float* w    = ws + OFF_W;
    const size_t off_f8 = (size_t)OFF_W + (size_t)3 * n;
    unsigned* S8 = (unsigned*)(ws + off_f8);
    const size_t off_p = off_f8 + (size_t)n * 4;
    float* ws_P = ws + off_p;

    const int n_tiles = (n + 15) >> 4;
    long avail = ((long)(ws_size / 4) - (long)off_p) / 4112;
    int grid1 = n_tiles < G1_MAX ? n_tiles : G1_MAX;
    if (avail < grid1) grid1 = (int)avail;
    if (grid1 < 1) grid1 = 1;

    hipMemsetAsync(ws_e, 0, SZ_E * sizeof(float), stream);
    hipMemsetAsync(ws_r, 0, 4112 * sizeof(float), stream);
    hipMemsetAsync(w, 0, (size_t)3 * n * sizeof(float), stream);

    k_rows<<<grid1, 256, 0, stream>>>(F, W, b, S_out, S8, ws_P, n, n_tiles);
    k_reduce<<<17 * NSEG, 256, 0, stream>>>(ws_P, ws_r, grid1);

    auto eg = [](int ne) { int g = (ne / 8 + 255) / 256; if (g < 1) g = 1;
                           return g < EGRID ? g : EGRID; };
    const int b0 = eg(nE), b1g = eg(n1), b2g = eg(n2);
    k_edge<<<b0 + b1g + b2g, 256, 0, stream>>>(
        adj_src, adj_dst, adj_val, nE,
        g1_src, g1_dst, g1_val, n1,
        g2_src, g2_dst, g2_val, n2,
        S8, w, ws_e, b0, b0 + b1g, n);

    k_dense<<<(n + 255) / 256, 256, 0, stream>>>(S_out, w, ws_e, n);
    k_ereduce<<<54, 256, 0, stream>>>(ws_e, ws_g);
    k_final<<<1, 256, 0, stream>>>(ws_r, ws_g, lamda_p, out, n);
}

// Round 6
// 156.293 us; speedup vs baseline: 2.8326x; 2.8326x over previous
//
#include <hip/hip_runtime.h>
#include <cstddef>
#include <cstdint>

// ---------------------------------------------------------------------------
// MultiGroupDMoN forward, reduced algebraically:
//   m_g   = sum_e val
//   tr_g  = sum_e val * dot(S[src], S[dst])      (fp8 rows, 1 uint4 gather each)
//   gdS_g = sum_e val * S[dst, :]                (fp8 decode, register acc)
// R6: revert R5's histogram atomics (199MB HBM write-through!). R4 structure
//     + fp8 S rows (16B) -> 2 gathers/edge, register gds, no per-edge atomics.
// ws layout (floats):
//   [OFF_E .. +3*18*EGRID)   edge partials [g][slot][block]
//   [OFF_R .. +4112)         reduced P[4096]+cs[16]   (memset 0)
//   [OFF_G .. +64)           G54 reduced accumulators
//   [OFF_F8.. +4n)           fp8 S (n rows x 16 bytes, as u32)
//   [OFF_P .. +grid1*4112)   per-block k_rows partials
// ---------------------------------------------------------------------------

#define G1_MAX   1024
#define EGRID    2048
#define NSEG     16
#define OFF_E    0
#define SZ_E     (3 * 18 * EGRID)
#define OFF_R    (OFF_E + SZ_E)
#define OFF_G    (OFF_R + 4112)
#define OFF_F8   (OFF_G + 64)

#if __has_builtin(__builtin_amdgcn_cvt_pk_f32_fp8)
#define HW_FP8 1
#endif

// ---- software e4m3fn encode (once per S element, in k_rows) ----
__device__ __forceinline__ unsigned f32_to_e4m3(float f)
{
    unsigned bits = __float_as_uint(f);
    unsigned s = bits >> 31;
    int e32 = (int)((bits >> 23) & 255);
    unsigned m23 = bits & 0x7FFFFF;
    int e = e32 - 120;                        // e4m3 biased exponent
    unsigned out;
    if (e32 == 0) out = 0;
    else if (e <= 0) {                        // denorm: round(|f|*512)
        float av = fabsf(f);
        int q = (int)(av * 512.0f + 0.5f);
        out = (unsigned)q;
    } else if (e > 15) out = (15u << 3) | 6u;
    else {
        unsigned m3 = (m23 + 0x80000u) >> 20;
        if (m3 == 8u) { m3 = 0u; ++e; if (e > 15) { e = 15; m3 = 6u; } }
        out = ((unsigned)e << 3) | m3;
    }
    return out | (s << 7);
}

// ---- decode 16 fp8 bytes (one S row) to floats, byte order preserved ----
__device__ __forceinline__ void decode16(uint4 r, float* o, const float* lut)
{
#ifdef HW_FP8
    #pragma unroll
    for (int j = 0; j < 4; ++j) {
        unsigned u = (&r.x)[j];
        auto lo = __builtin_amdgcn_cvt_pk_f32_fp8(u, false);   // bytes 0,1
        auto hi = __builtin_amdgcn_cvt_pk_f32_fp8(u, true);    // bytes 2,3
        o[4*j]   = lo[0]; o[4*j+1] = lo[1];
        o[4*j+2] = hi[0]; o[4*j+3] = hi[1];
    }
#else
    #pragma unroll
    for (int j = 0; j < 4; ++j) {
        unsigned u = (&r.x)[j];
        #pragma unroll
        for (int q = 0; q < 4; ++q)
            o[4*j+q] = lut[(u >> (8*q)) & 255];
    }
#endif
}

__global__ void __launch_bounds__(256)
k_rows(const float* __restrict__ F, const float* __restrict__ W,
       const float* __restrict__ b, float* __restrict__ S_out,
       unsigned* __restrict__ S_f8, float* __restrict__ ws_P, int n, int n_tiles)
{
    __shared__ float Wt[16][260];
    __shared__ float rows[16][260];
    __shared__ float S_lds[16][17];
    __shared__ float cs_red[256];

    const int t = threadIdx.x;

    for (int idx = t; idx < 4096; idx += 256)
        Wt[idx & 15][idx >> 4] = W[idx];

    const float bk = b[t & 15];
    const int rl = t >> 4;
    const int kl = t & 15;
    const int kp = t & 15;
    const int cp = t >> 4;

    float4 P0 = {0,0,0,0}, P1 = {0,0,0,0}, P2 = {0,0,0,0}, P3 = {0,0,0,0};
    float cs_acc = 0.f;
    __syncthreads();

    for (int tile = blockIdx.x; tile < n_tiles; tile += gridDim.x) {
        const int row0 = tile << 4;
        const float4* F4 = (const float4*)(F + (size_t)row0 * 256);
        #pragma unroll
        for (int q = 0; q < 4; ++q) {
            int idx = t + (q << 8);
            int r = idx >> 6, dc = idx & 63;
            float4 v = {0.f, 0.f, 0.f, 0.f};
            if (row0 + r < n) v = F4[idx];
            *(float4*)&rows[r][dc << 2] = v;
        }
        __syncthreads();

        float acc = 0.f;
        #pragma unroll 8
        for (int dd = 0; dd < 64; ++dd) {
            float4 f4 = *(const float4*)&rows[rl][dd << 2];
            float4 w4 = *(const float4*)&Wt[kl][dd << 2];
            acc = fmaf(f4.x, w4.x, acc);
            acc = fmaf(f4.y, w4.y, acc);
            acc = fmaf(f4.z, w4.z, acc);
            acc = fmaf(f4.w, w4.w, acc);
        }
        acc += bk;

        float mx = acc;
        #pragma unroll
        for (int o = 8; o; o >>= 1) mx = fmaxf(mx, __shfl_xor(mx, o, 16));
        float ev = __expf(acc - mx);
        float sm = ev;
        #pragma unroll
        for (int o = 8; o; o >>= 1) sm += __shfl_xor(sm, o, 16);
        float sval = ev / sm;

        const bool valid = (row0 + rl) < n;
        if (valid) {
            S_out[(((size_t)(row0 + rl)) << 4) + kl] = sval;
            cs_acc += sval;
        }
        S_lds[rl][kl] = valid ? sval : 0.f;
        __syncthreads();

        // fp8 pack: thread t<64 packs row r=t>>2, 4-elem chunk c=t&3
        if (t < 64) {
            int r = t >> 2, c = t & 3;
            int row = row0 + r;
            if (row < n) {
                unsigned u = f32_to_e4m3(S_lds[r][4*c])
                           | (f32_to_e4m3(S_lds[r][4*c+1]) << 8)
                           | (f32_to_e4m3(S_lds[r][4*c+2]) << 16)
                           | (f32_to_e4m3(S_lds[r][4*c+3]) << 24);
                S_f8[((size_t)row << 2) + c] = u;
            }
        }

        #pragma unroll 4
        for (int r = 0; r < 16; ++r) {
            float sv = S_lds[r][kp];
            const float* rp = &rows[r][cp << 4];
            float4 f0 = *(const float4*)&rp[0];
            float4 f1 = *(const float4*)&rp[4];
            float4 f2 = *(const float4*)&rp[8];
            float4 f3 = *(const float4*)&rp[12];
            P0.x = fmaf(sv, f0.x, P0.x); P0.y = fmaf(sv, f0.y, P0.y);
            P0.z = fmaf(sv, f0.z, P0.z); P0.w = fmaf(sv, f0.w, P0.w);
            P1.x = fmaf(sv, f1.x, P1.x); P1.y = fmaf(sv, f1.y, P1.y);
            P1.z = fmaf(sv, f1.z, P1.z); P1.w = fmaf(sv, f1.w, P1.w);
            P2.x = fmaf(sv, f2.x, P2.x); P2.y = fmaf(sv, f2.y, P2.y);
            P2.z = fmaf(sv, f2.z, P2.z); P2.w = fmaf(sv, f2.w, P2.w);
            P3.x = fmaf(sv, f3.x, P3.x); P3.y = fmaf(sv, f3.y, P3.y);
            P3.z = fmaf(sv, f3.z, P3.z); P3.w = fmaf(sv, f3.w, P3.w);
        }
        __syncthreads();
    }

    {
        float* dst = ws_P + (size_t)blockIdx.x * 4112 + kp * 256 + (cp << 4);
        *(float4*)&dst[0]  = P0;
        *(float4*)&dst[4]  = P1;
        *(float4*)&dst[8]  = P2;
        *(float4*)&dst[12] = P3;
    }
    cs_red[t] = cs_acc;
    __syncthreads();
    if (t < 16) {
        float ssum = 0.f;
        #pragma unroll
        for (int i = 0; i < 16; ++i) ssum += cs_red[t + (i << 4)];
        ws_P[(size_t)blockIdx.x * 4112 + 4096 + t] = ssum;
    }
}

__global__ void __launch_bounds__(256)
k_reduce(const float* __restrict__ ws_P, float* __restrict__ ws_red, int nb)
{
    const int seg  = blockIdx.x & (NSEG - 1);
    const int jblk = blockIdx.x / NSEG;
    const int idx  = jblk * 256 + threadIdx.x;
    if (idx >= 4112) return;
    const int chunk = (nb + NSEG - 1) / NSEG;
    const int b0 = seg * chunk;
    const int b1 = min(nb, b0 + chunk);
    float s = 0.f;
    for (int bb = b0; bb < b1; ++bb)
        s += ws_P[(size_t)bb * 4112 + idx];
    atomicAdd(&ws_red[idx], s);
}

// fused edge kernel, all 3 graphs; register accumulators, no per-edge atomics
__global__ void __launch_bounds__(256, 2)
k_edge(const int* __restrict__ src0, const int* __restrict__ dst0,
       const float* __restrict__ val0, int n0,
       const int* __restrict__ src1, const int* __restrict__ dst1,
       const float* __restrict__ val1, int n1,
       const int* __restrict__ src2, const int* __restrict__ dst2,
       const float* __restrict__ val2, int n2,
       const uint4* __restrict__ S8, float* __restrict__ ws_e,
       int b0, int b1)
{
#ifndef HW_FP8
    __shared__ float lut[256];
    if (threadIdx.x < 256) {
        int i = threadIdx.x;
        int e_ = (i >> 3) & 15, m_ = i & 7, s_ = i >> 7;
        float v = e_ ? ldexpf((float)(8 + m_), e_ - 10) : ldexpf((float)m_, -9);
        lut[i] = s_ ? -v : v;
    }
    __syncthreads();
    const float* lutp = lut;
#else
    const float* lutp = nullptr;
#endif

    int g, bb, nblk, nE;
    const int* src; const int* dst; const float* val;
    if ((int)blockIdx.x < b0)      { g = 0; bb = blockIdx.x;      nblk = b0;             src = src0; dst = dst0; val = val0; nE = n0; }
    else if ((int)blockIdx.x < b1) { g = 1; bb = blockIdx.x - b0; nblk = b1 - b0;        src = src1; dst = dst1; val = val1; nE = n1; }
    else                           { g = 2; bb = blockIdx.x - b1; nblk = gridDim.x - b1; src = src2; dst = dst2; val = val2; nE = n2; }

    float m_acc = 0.f, tr_acc = 0.f;
    float gds[16];
    #pragma unroll
    for (int k = 0; k < 16; ++k) gds[k] = 0.f;

    const int nv = nE >> 3;                    // 8 edges per thread-iter
    const int4*   s4 = (const int4*)src;
    const int4*   d4 = (const int4*)dst;
    const float4* v4 = (const float4*)val;
    const int stride = nblk * 256;

    for (int i = bb * 256 + threadIdx.x; i < nv; i += stride) {
        int4   sa = s4[2*i], sb = s4[2*i+1];
        int4   da = d4[2*i], db = d4[2*i+1];
        float4 va = v4[2*i], vb = v4[2*i+1];
        int   is[8] = {sa.x, sa.y, sa.z, sa.w, sb.x, sb.y, sb.z, sb.w};
        int   id[8] = {da.x, da.y, da.z, da.w, db.x, db.y, db.z, db.w};
        float vv[8] = {va.x, va.y, va.z, va.w, vb.x, vb.y, vb.z, vb.w};
        uint4 rs[8], rd[8];
        #pragma unroll
        for (int e = 0; e < 8; ++e) {
            rs[e] = S8[is[e]];
            rd[e] = S8[id[e]];
        }
        #pragma unroll
        for (int e = 0; e < 8; ++e) {
            float sv[16], dv[16];
            decode16(rs[e], sv, lutp);
            decode16(rd[e], dv, lutp);
            float v = vv[e];
            float dot = 0.f;
            #pragma unroll
            for (int k = 0; k < 16; ++k) dot = fmaf(sv[k], dv[k], dot);
            m_acc += v;
            tr_acc = fmaf(v, dot, tr_acc);
            #pragma unroll
            for (int k = 0; k < 16; ++k) gds[k] = fmaf(v, dv[k], gds[k]);
        }
    }

    // tail (nE % 8): handled by block 0 of this graph
    if (bb == 0) {
        int e = (nv << 3) + threadIdx.x;
        if (e < nE) {
            float sv[16], dv[16];
            decode16(S8[src[e]], sv, lutp);
            decode16(S8[dst[e]], dv, lutp);
            float v = val[e];
            float dot = 0.f;
            #pragma unroll
            for (int k = 0; k < 16; ++k) dot = fmaf(sv[k], dv[k], dot);
            m_acc += v;
            tr_acc = fmaf(v, dot, tr_acc);
            #pragma unroll
            for (int k = 0; k < 16; ++k) gds[k] = fmaf(v, dv[k], gds[k]);
        }
    }

    #pragma unroll
    for (int o = 32; o; o >>= 1) {
        m_acc  += __shfl_xor(m_acc, o);
        tr_acc += __shfl_xor(tr_acc, o);
        #pragma unroll
        for (int k = 0; k < 16; ++k) gds[k] += __shfl_xor(gds[k], o);
    }
    __shared__ float wred[4][18];
    const int wid = threadIdx.x >> 6, lane = threadIdx.x & 63;
    if (lane == 0) {
        wred[wid][0] = m_acc; wred[wid][1] = tr_acc;
        #pragma unroll
        for (int k = 0; k < 16; ++k) wred[wid][2 + k] = gds[k];
    }
    __syncthreads();
    if (threadIdx.x < 18) {
        float s = wred[0][threadIdx.x] + wred[1][threadIdx.x]
                + wred[2][threadIdx.x] + wred[3][threadIdx.x];
        ws_e[(size_t)g * 18 * EGRID + (size_t)threadIdx.x * EGRID + bb] = s;
    }
}

// one block per (g,slot): coalesced reduce of per-graph partials -> G54
__global__ void __launch_bounds__(256)
k_ereduce(const float* __restrict__ ws_e, float* __restrict__ G54,
          int g0, int g1, int g2)
{
    const int p = blockIdx.x;            // 0..53
    const int g = p / 18, slot = p % 18;
    int grids[3] = {g0, g1, g2};
    const int gb = grids[g];
    const float* base = ws_e + (size_t)g * 18 * EGRID + (size_t)slot * EGRID;

    const int t = threadIdx.x;
    float s = 0.f;
    for (int bb = t; bb < gb; bb += 256) s += base[bb];
    #pragma unroll
    for (int o = 32; o; o >>= 1) s += __shfl_xor(s, o);

    __shared__ float wr[4];
    if ((t & 63) == 0) wr[t >> 6] = s;
    __syncthreads();
    if (t == 0) G54[p] = wr[0] + wr[1] + wr[2] + wr[3];
}

__global__ void __launch_bounds__(256)
k_final(const float* __restrict__ ws_red, const float* __restrict__ G54,
        const void* __restrict__ lamda_ptr, float* __restrict__ out, int n)
{
    __shared__ float G[54];
    const int t = threadIdx.x;
    if (t < 54) G[t] = G54[t];
    __syncthreads();

    const float* P  = ws_red;
    const float* cs = ws_red + 4096;

    const float scale = 1.0507009873554805f;
    const float alpha = 1.6732632423543772f;
    for (int idx = t; idx < 4096; idx += 256) {
        int k = idx >> 8;
        float x = P[idx] / cs[k];
        float y = x > 0.f ? scale * x : scale * alpha * (expf(x) - 1.f);
        out[idx] = y;
    }

    if (t == 0) {
        int   li = *(const int*)lamda_ptr;
        float lf = *(const float*)lamda_ptr;
        float lamda = (li > -100000 && li < 100000) ? (float)li : lf;

        float m = G[0], trA = G[1];
        float ds2 = 0.f;
        for (int k = 0; k < 16; ++k) ds2 += G[2 + k] * G[2 + k];
        float spectral = -(trA - ds2 / (2.f * m)) / (2.f * m);

        float Q[2], gm[2];
        for (int g = 0; g < 2; ++g) {
            const float* Gg = G + 18 * (g + 1);
            float mg = Gg[0], trg = Gg[1];
            float gds2 = 0.f;
            for (int k = 0; k < 16; ++k) gds2 += Gg[2 + k] * Gg[2 + k];
            float safe = mg > 0.f ? mg : 1.f;
            float q = (trg - gds2 / (2.f * safe)) / (2.f * m);
            Q[g]  = mg > 0.f ? q : 0.f;
            gm[g] = mg;
        }
        float Qmin = fminf(Q[0], Q[1]);
        float gmean = 0.5f * (gm[0] + gm[1]);
        float fairness = (m / (gmean + 1e-8f)) * (-Qmin);

        float csn = 0.f;
        for (int k = 0; k < 16; ++k) csn += cs[k] * cs[k];
        float collapse = (sqrtf(csn) / (float)n) * 4.f - 1.f;

        out[4096 + (size_t)n * 16] = spectral + lamda * fairness + 0.1f * collapse;
    }
}

extern "C" void kernel_launch(void* const* d_in, const int* in_sizes, int n_in,
                              void* d_out, int out_size, void* d_ws, size_t ws_size,
                              hipStream_t stream)
{
    const float* F       = (const float*)d_in[0];
    const float* W       = (const float*)d_in[1];
    const float* b       = (const float*)d_in[2];
    const int*   adj_src = (const int*)d_in[3];
    const int*   adj_dst = (const int*)d_in[4];
    const float* adj_val = (const float*)d_in[5];
    const int*   g1_src  = (const int*)d_in[6];
    const int*   g1_dst  = (const int*)d_in[7];
    const float* g1_val  = (const float*)d_in[8];
    const int*   g2_src  = (const int*)d_in[9];
    const int*   g2_dst  = (const int*)d_in[10];
    const float* g2_val  = (const float*)d_in[11];
    const void*  lamda_p = d_in[12];

    const int n  = in_sizes[0] / 256;
    const int nE = in_sizes[3];
    const int n1 = in_sizes[6];
    const int n2 = in_sizes[9];

    float* out   = (float*)d_out;
    float* S_out = out + 4096;

    float* ws   = (float*)d_ws;
    float* ws_e = ws + OFF_E;
    float* ws_r = ws + OFF_R;
    float* ws_g = ws + OFF_G;
    unsigned* S8 = (unsigned*)(ws + OFF_F8);
    const size_t off_p = (size_t)OFF_F8 + (size_t)n * 4;
    float* ws_P = ws + off_p;

    const int n_tiles = (n + 15) >> 4;
    long avail = ((long)(ws_size / 4) - (long)off_p) / 4112;
    int grid1 = n_tiles < G1_MAX ? n_tiles : G1_MAX;
    if (avail < grid1) grid1 = (int)avail;
    if (grid1 < 1) grid1 = 1;

    hipMemsetAsync(ws_r, 0, 4112 * sizeof(float), stream);

    k_rows<<<grid1, 256, 0, stream>>>(F, W, b, S_out, S8, ws_P, n, n_tiles);
    k_reduce<<<17 * NSEG, 256, 0, stream>>>(ws_P, ws_r, grid1);

    auto eg = [](int ne) { int g = (ne / 8 + 255) / 256; if (g < 1) g = 1;
                           return g < EGRID ? g : EGRID; };
    const int b0 = eg(nE), b1g = eg(n1), b2g = eg(n2);
    k_edge<<<b0 + b1g + b2g, 256, 0, stream>>>(
        adj_src, adj_dst, adj_val, nE,
        g1_src, g1_dst, g1_val, n1,
        g2_src, g2_dst, g2_val, n2,
        (const uint4*)S8, ws_e, b0, b0 + b1g);

    k_ereduce<<<54, 256, 0, stream>>>(ws_e, ws_g, b0, b1g, b2g);
    k_final<<<1, 256, 0, stream>>>(ws_r, ws_g, lamda_p, out, n);
}